// Round 1
// baseline (604.791 us; speedup 1.0000x reference)
//
#include <hip/hip_runtime.h>
#include <math.h>

typedef __bf16 bf16_t;
typedef __bf16 bf16x2 __attribute__((ext_vector_type(2)));
typedef __bf16 bf16x4 __attribute__((ext_vector_type(4)));
typedef __bf16 bf16x8 __attribute__((ext_vector_type(8)));
typedef float f32x4 __attribute__((ext_vector_type(4)));

#define NB   32
#define SEQ  2048
#define HD   128
#define BM   64    // q rows per block (16 per wave)
#define BN   64    // keys per K-loop iteration
#define KPAD 8     // pad to 136 shorts/row: 272B stride -> 2-way LDS reads (free)
#define VPAD 8     // pad to 72 shorts/row: 144B stride, 16B aligned
#define PPAD 8
#define SCALE 0.08838834764831845f

__global__ __launch_bounds__(256) void fa_kernel(
    const float* __restrict__ Q, const float* __restrict__ K,
    const float* __restrict__ V, float* __restrict__ O)
{
  __shared__ __attribute__((aligned(16))) bf16_t Ksh[BN][HD + KPAD];   // [key][d]
  __shared__ __attribute__((aligned(16))) bf16_t Vsh[HD][BN + VPAD];   // [d][key] (transposed)
  __shared__ __attribute__((aligned(16))) bf16_t Psh[4][16][BN + PPAD];// per-wave P transpose buf

  const int tid  = threadIdx.x;
  const int lane = tid & 63;
  const int wq   = tid >> 6;   // wave id 0..3
  const int quad = lane >> 4;  // 0..3
  const int l15  = lane & 15;

  const int bid   = blockIdx.x;
  const int batch = bid >> 5;  // SEQ/BM = 32 q-tiles per batch
  const int qt    = bid & 31;

  const float* Qb = Q + (size_t)batch * SEQ * HD + (size_t)qt * BM * HD;
  const float* Kb = K + (size_t)batch * SEQ * HD;
  const float* Vb = V + (size_t)batch * SEQ * HD;
  float*       Ob = O + (size_t)batch * SEQ * HD + (size_t)qt * BM * HD;

  // ---- Q fragments, A-operand layout: A[m=l15][k=quad*8+j], kf tiles of 32 ----
  bf16x8 aq[4];
  {
    const int qrow = wq * 16 + l15;
    for (int kf = 0; kf < 4; ++kf) {
      const float* qp = Qb + (size_t)qrow * HD + kf * 32 + quad * 8;
      float4 x0 = *(const float4*)(qp);
      float4 x1 = *(const float4*)(qp + 4);
      bf16x8 a;
      a[0] = (bf16_t)x0.x; a[1] = (bf16_t)x0.y; a[2] = (bf16_t)x0.z; a[3] = (bf16_t)x0.w;
      a[4] = (bf16_t)x1.x; a[5] = (bf16_t)x1.y; a[6] = (bf16_t)x1.z; a[7] = (bf16_t)x1.w;
      aq[kf] = a;
    }
  }

  f32x4 o[8];
  for (int t = 0; t < 8; ++t) { o[t][0] = 0.f; o[t][1] = 0.f; o[t][2] = 0.f; o[t][3] = 0.f; }
  float m_r[4], l_r[4];
  for (int r = 0; r < 4; ++r) { m_r[r] = -INFINITY; l_r[r] = 0.0f; }

  const int vkp = (tid & 31) * 2;  // key pair base 0..62
  const int vg  = tid >> 5;        // 0..7

  for (int kb = 0; kb < SEQ; kb += BN) {
    __syncthreads();  // previous iter's frag reads done before restage

    // ---- stage K tile: Ksh[key][d], coalesced float4 reads, b64 LDS writes ----
    for (int i = 0; i < 8; ++i) {
      int v   = tid + i * 256;       // 0..2047
      int row = v >> 5;              // 0..63
      int c4  = (v & 31) * 4;        // 0..124
      float4 kv = *(const float4*)(Kb + (size_t)(kb + row) * HD + c4);
      bf16x4 kk;
      kk[0] = (bf16_t)kv.x; kk[1] = (bf16_t)kv.y; kk[2] = (bf16_t)kv.z; kk[3] = (bf16_t)kv.w;
      *(bf16x4*)&Ksh[row][c4] = kk;
    }
    // ---- stage V transposed: Vsh[d][key]; lane<->key so LDS writes are conflict-free b32 ----
    for (int i = 0; i < 4; ++i) {
      int d0 = (vg + i * 8) * 4;     // 0..124
      const float* vp0 = Vb + (size_t)(kb + vkp) * HD + d0;
      float4 a0 = *(const float4*)vp0;
      float4 a1 = *(const float4*)(vp0 + HD);
      bf16x2 p0; p0[0] = (bf16_t)a0.x; p0[1] = (bf16_t)a1.x;
      bf16x2 p1; p1[0] = (bf16_t)a0.y; p1[1] = (bf16_t)a1.y;
      bf16x2 p2; p2[0] = (bf16_t)a0.z; p2[1] = (bf16_t)a1.z;
      bf16x2 p3; p3[0] = (bf16_t)a0.w; p3[1] = (bf16_t)a1.w;
      *(bf16x2*)&Vsh[d0 + 0][vkp] = p0;
      *(bf16x2*)&Vsh[d0 + 1][vkp] = p1;
      *(bf16x2*)&Vsh[d0 + 2][vkp] = p2;
      *(bf16x2*)&Vsh[d0 + 3][vkp] = p3;
    }
    __syncthreads();

    // ---- S = Q K^T (16 x 64 per wave); B-frag: B[k=d][n=key] from Ksh rows ----
    f32x4 s[4];
    for (int ct = 0; ct < 4; ++ct) { s[ct][0]=0.f; s[ct][1]=0.f; s[ct][2]=0.f; s[ct][3]=0.f; }
    for (int kf = 0; kf < 4; ++kf) {
      for (int ct = 0; ct < 4; ++ct) {
        bf16x8 bk = *(const bf16x8*)&Ksh[ct * 16 + l15][kf * 32 + quad * 8];
        s[ct] = __builtin_amdgcn_mfma_f32_16x16x32_bf16(aq[kf], bk, s[ct], 0, 0, 0);
      }
    }
    for (int ct = 0; ct < 4; ++ct) s[ct] *= SCALE;

    // ---- online softmax; row q = quad*4+reg, cols on l15 -> shfl_xor reduce ----
    float alpha[4];
    for (int r = 0; r < 4; ++r) {
      float mx = fmaxf(fmaxf(s[0][r], s[1][r]), fmaxf(s[2][r], s[3][r]));
      mx = fmaxf(mx, __shfl_xor(mx, 1));
      mx = fmaxf(mx, __shfl_xor(mx, 2));
      mx = fmaxf(mx, __shfl_xor(mx, 4));
      mx = fmaxf(mx, __shfl_xor(mx, 8));
      float mnew = fmaxf(m_r[r], mx);
      alpha[r] = __expf(m_r[r] - mnew);
      m_r[r] = mnew;
      float rs = 0.f;
      for (int ct = 0; ct < 4; ++ct) {
        float p = __expf(s[ct][r] - mnew);
        s[ct][r] = p;
        rs += p;
      }
      rs += __shfl_xor(rs, 1);
      rs += __shfl_xor(rs, 2);
      rs += __shfl_xor(rs, 4);
      rs += __shfl_xor(rs, 8);
      l_r[r] = l_r[r] * alpha[r] + rs;
    }

    // ---- P: C/D layout -> LDS -> A-operand layout ----
    for (int ct = 0; ct < 4; ++ct)
      for (int r = 0; r < 4; ++r)
        Psh[wq][quad * 4 + r][ct * 16 + l15] = (bf16_t)s[ct][r];
    asm volatile("s_waitcnt lgkmcnt(0)" ::: "memory");
    bf16x8 ap0 = *(const bf16x8*)&Psh[wq][l15][quad * 8];
    bf16x8 ap1 = *(const bf16x8*)&Psh[wq][l15][32 + quad * 8];

    // ---- rescale O, accumulate O += P V ----
    for (int t = 0; t < 8; ++t) {
      o[t][0] *= alpha[0]; o[t][1] *= alpha[1];
      o[t][2] *= alpha[2]; o[t][3] *= alpha[3];
    }
    for (int t = 0; t < 8; ++t) {
      bf16x8 bv0 = *(const bf16x8*)&Vsh[t * 16 + l15][quad * 8];
      o[t] = __builtin_amdgcn_mfma_f32_16x16x32_bf16(ap0, bv0, o[t], 0, 0, 0);
      bf16x8 bv1 = *(const bf16x8*)&Vsh[t * 16 + l15][32 + quad * 8];
      o[t] = __builtin_amdgcn_mfma_f32_16x16x32_bf16(ap1, bv1, o[t], 0, 0, 0);
    }
  }

  // ---- epilogue: O /= l, write out ----
  float inv[4];
  for (int r = 0; r < 4; ++r) inv[r] = 1.0f / l_r[r];
  for (int t = 0; t < 8; ++t) {
    for (int r = 0; r < 4; ++r) {
      Ob[(size_t)(wq * 16 + quad * 4 + r) * HD + t * 16 + l15] = o[t][r] * inv[r];
    }
  }
}

extern "C" void kernel_launch(void* const* d_in, const int* in_sizes, int n_in,
                              void* d_out, int out_size, void* d_ws, size_t ws_size,
                              hipStream_t stream) {
  const float* q = (const float*)d_in[0];
  const float* k = (const float*)d_in[1];
  const float* v = (const float*)d_in[2];
  float* out = (float*)d_out;
  dim3 grid(NB * (SEQ / BM));   // 1024 blocks
  dim3 block(256);
  fa_kernel<<<grid, block, 0, stream>>>(q, k, v, out);
}

// Round 2
// 365.019 us; speedup vs baseline: 1.6569x; 1.6569x over previous
//
#include <hip/hip_runtime.h>
#include <math.h>

typedef __bf16 bf16_t;
typedef __bf16 bf16x2 __attribute__((ext_vector_type(2)));
typedef __bf16 bf16x4 __attribute__((ext_vector_type(4)));
typedef __bf16 bf16x8 __attribute__((ext_vector_type(8)));
typedef float f32x4 __attribute__((ext_vector_type(4)));

#define NB   32
#define SEQ  2048
#define HD   128
#define BM   64    // q rows per block (16 per wave)
#define BN   64    // keys per K-loop iteration
#define KPAD 8     // 136 shorts/row: 272B stride, 16B-aligned, 2-way LDS (free)
#define VPAD 8     // 72 shorts/row
#define PPAD 8
#define SCALE 0.08838834764831845f

__global__ __launch_bounds__(256) void fa_kernel(
    const float* __restrict__ Q, const float* __restrict__ K,
    const float* __restrict__ V, float* __restrict__ O)
{
  __shared__ __attribute__((aligned(16))) bf16_t Ksh[BN][HD + KPAD];    // [key][d]
  __shared__ __attribute__((aligned(16))) bf16_t Vsh[HD][BN + VPAD];    // [d][key]
  __shared__ __attribute__((aligned(16))) bf16_t Psh[4][16][BN + PPAD]; // per-wave [q][key]

  const int tid  = threadIdx.x;
  const int lane = tid & 63;
  const int wq   = tid >> 6;   // wave id 0..3
  const int quad = lane >> 4;  // 0..3
  const int l15  = lane & 15;

  const int bid   = blockIdx.x;
  const int batch = bid >> 5;
  const int qt    = bid & 31;

  const float* Qb = Q + (size_t)batch * SEQ * HD + (size_t)qt * BM * HD;
  const float* Kb = K + (size_t)batch * SEQ * HD;
  const float* Vb = V + (size_t)batch * SEQ * HD;
  float*       Ob = O + (size_t)batch * SEQ * HD + (size_t)qt * BM * HD;

  // ---- Q fragments (B-operand for S^T): B[n=q=l15][k=d=quad*8+j], SCALE folded in ----
  bf16x8 aq[4];
  {
    const int qrow = wq * 16 + l15;
#pragma unroll
    for (int kf = 0; kf < 4; ++kf) {
      const float* qp = Qb + (size_t)qrow * HD + kf * 32 + quad * 8;
      float4 x0 = *(const float4*)(qp);
      float4 x1 = *(const float4*)(qp + 4);
      bf16x8 a;
      a[0] = (bf16_t)(x0.x * SCALE); a[1] = (bf16_t)(x0.y * SCALE);
      a[2] = (bf16_t)(x0.z * SCALE); a[3] = (bf16_t)(x0.w * SCALE);
      a[4] = (bf16_t)(x1.x * SCALE); a[5] = (bf16_t)(x1.y * SCALE);
      a[6] = (bf16_t)(x1.z * SCALE); a[7] = (bf16_t)(x1.w * SCALE);
      aq[kf] = a;
    }
  }

  f32x4 o[8];
#pragma unroll
  for (int t = 0; t < 8; ++t) { o[t][0] = 0.f; o[t][1] = 0.f; o[t][2] = 0.f; o[t][3] = 0.f; }
  float m_r = -INFINITY, l_r = 0.0f;   // per-lane: q = l15 (replicated across quads)

  const int vkp = (tid & 31) * 2;  // key pair base 0..62
  const int vg  = tid >> 5;        // 0..7

  // prefetch registers for next tile
  float4 kreg[8], vreg[8];

  // ---- preload tile 0 ----
#pragma unroll
  for (int i = 0; i < 8; ++i) {
    int v = tid + i * 256, row = v >> 5, c4 = (v & 31) * 4;
    kreg[i] = *(const float4*)(Kb + (size_t)row * HD + c4);
  }
#pragma unroll
  for (int i = 0; i < 4; ++i) {
    int d0 = (vg + i * 8) * 4;
    const float* vp0 = Vb + (size_t)vkp * HD + d0;
    vreg[2 * i]     = *(const float4*)vp0;
    vreg[2 * i + 1] = *(const float4*)(vp0 + HD);
  }

  for (int kb = 0; kb < SEQ; kb += BN) {
    __syncthreads();  // all waves done reading LDS of previous iter

    // ---- write staged tile (regs -> LDS, with cvt); vmcnt waits auto ----
#pragma unroll
    for (int i = 0; i < 8; ++i) {
      int v = tid + i * 256, row = v >> 5, c4 = (v & 31) * 4;
      float4 kv = kreg[i];
      bf16x4 kk;
      kk[0] = (bf16_t)kv.x; kk[1] = (bf16_t)kv.y; kk[2] = (bf16_t)kv.z; kk[3] = (bf16_t)kv.w;
      *(bf16x4*)&Ksh[row][c4] = kk;
    }
#pragma unroll
    for (int i = 0; i < 4; ++i) {
      int d0 = (vg + i * 8) * 4;
      float4 a0 = vreg[2 * i];
      float4 a1 = vreg[2 * i + 1];
      bf16x2 p0; p0[0] = (bf16_t)a0.x; p0[1] = (bf16_t)a1.x;
      bf16x2 p1; p1[0] = (bf16_t)a0.y; p1[1] = (bf16_t)a1.y;
      bf16x2 p2; p2[0] = (bf16_t)a0.z; p2[1] = (bf16_t)a1.z;
      bf16x2 p3; p3[0] = (bf16_t)a0.w; p3[1] = (bf16_t)a1.w;
      *(bf16x2*)&Vsh[d0 + 0][vkp] = p0;
      *(bf16x2*)&Vsh[d0 + 1][vkp] = p1;
      *(bf16x2*)&Vsh[d0 + 2][vkp] = p2;
      *(bf16x2*)&Vsh[d0 + 3][vkp] = p3;
    }
    __syncthreads();

    // ---- prefetch next tile into regs (no wait; hides behind compute) ----
    const int kbn = kb + BN;
    if (kbn < SEQ) {
#pragma unroll
      for (int i = 0; i < 8; ++i) {
        int v = tid + i * 256, row = v >> 5, c4 = (v & 31) * 4;
        kreg[i] = *(const float4*)(Kb + (size_t)(kbn + row) * HD + c4);
      }
#pragma unroll
      for (int i = 0; i < 4; ++i) {
        int d0 = (vg + i * 8) * 4;
        const float* vp0 = Vb + (size_t)(kbn + vkp) * HD + d0;
        vreg[2 * i]     = *(const float4*)vp0;
        vreg[2 * i + 1] = *(const float4*)(vp0 + HD);
      }
    }

    // ---- S^T = K Q^T (64 keys x 16 q per wave): A=K, B=Q ----
    // st[ct][r] = S[q=l15][key = ct*16 + quad*4 + r]
    f32x4 st[4];
#pragma unroll
    for (int ct = 0; ct < 4; ++ct) { st[ct][0]=0.f; st[ct][1]=0.f; st[ct][2]=0.f; st[ct][3]=0.f; }
#pragma unroll
    for (int kf = 0; kf < 4; ++kf) {
#pragma unroll
      for (int ct = 0; ct < 4; ++ct) {
        bf16x8 ak = *(const bf16x8*)&Ksh[ct * 16 + l15][kf * 32 + quad * 8];
        st[ct] = __builtin_amdgcn_mfma_f32_16x16x32_bf16(ak, aq[kf], st[ct], 0, 0, 0);
      }
    }

    // ---- online softmax: in-lane over 16 regs + 2 shfl_xor across quads ----
    float mx = st[0][0];
#pragma unroll
    for (int ct = 0; ct < 4; ++ct)
#pragma unroll
      for (int r = 0; r < 4; ++r) mx = fmaxf(mx, st[ct][r]);
    mx = fmaxf(mx, __shfl_xor(mx, 16));
    mx = fmaxf(mx, __shfl_xor(mx, 32));
    float mnew = fmaxf(m_r, mx);
    float alpha = __expf(m_r - mnew);
    m_r = mnew;
    float ls = 0.f;
#pragma unroll
    for (int ct = 0; ct < 4; ++ct)
#pragma unroll
      for (int r = 0; r < 4; ++r) {
        float p = __expf(st[ct][r] - mnew);
        st[ct][r] = p;
        ls += p;
      }
    ls += __shfl_xor(ls, 16);
    ls += __shfl_xor(ls, 32);
    l_r = l_r * alpha + ls;

    // ---- P -> per-wave LDS [q][key] (b64 writes), re-read as B-frags ----
#pragma unroll
    for (int ct = 0; ct < 4; ++ct) {
      bf16x4 pp;
      pp[0] = (bf16_t)st[ct][0]; pp[1] = (bf16_t)st[ct][1];
      pp[2] = (bf16_t)st[ct][2]; pp[3] = (bf16_t)st[ct][3];
      *(bf16x4*)&Psh[wq][l15][ct * 16 + quad * 4] = pp;
    }
    asm volatile("s_waitcnt lgkmcnt(0)" ::: "memory");
    bf16x8 ap0 = *(const bf16x8*)&Psh[wq][l15][quad * 8];
    bf16x8 ap1 = *(const bf16x8*)&Psh[wq][l15][32 + quad * 8];

    // ---- rescale O (alpha uniform per lane), O^T += V^T P^T ----
#pragma unroll
    for (int t = 0; t < 8; ++t) {
      o[t][0] *= alpha; o[t][1] *= alpha; o[t][2] *= alpha; o[t][3] *= alpha;
    }
#pragma unroll
    for (int t = 0; t < 8; ++t) {
      bf16x8 av0 = *(const bf16x8*)&Vsh[t * 16 + l15][quad * 8];
      o[t] = __builtin_amdgcn_mfma_f32_16x16x32_bf16(av0, ap0, o[t], 0, 0, 0);
      bf16x8 av1 = *(const bf16x8*)&Vsh[t * 16 + l15][32 + quad * 8];
      o[t] = __builtin_amdgcn_mfma_f32_16x16x32_bf16(av1, ap1, o[t], 0, 0, 0);
    }
  }

  // ---- epilogue: O[q][d] = O^T[d][q] / l ; o[dt][r] = O[q=l15][d=dt*16+quad*4+r] ----
  float inv = 1.0f / l_r;
  const int qrow = wq * 16 + l15;
#pragma unroll
  for (int t = 0; t < 8; ++t) {
    float4 w;
    w.x = o[t][0] * inv; w.y = o[t][1] * inv;
    w.z = o[t][2] * inv; w.w = o[t][3] * inv;
    *(float4*)&Ob[(size_t)qrow * HD + t * 16 + quad * 4] = w;
  }
}

extern "C" void kernel_launch(void* const* d_in, const int* in_sizes, int n_in,
                              void* d_out, int out_size, void* d_ws, size_t ws_size,
                              hipStream_t stream) {
  const float* q = (const float*)d_in[0];
  const float* k = (const float*)d_in[1];
  const float* v = (const float*)d_in[2];
  float* out = (float*)d_out;
  dim3 grid(NB * (SEQ / BM));   // 1024 blocks
  dim3 block(256);
  fa_kernel<<<grid, block, 0, stream>>>(q, k, v, out);
}

// Round 5
// 250.437 us; speedup vs baseline: 2.4149x; 1.4575x over previous
//
#include <hip/hip_runtime.h>
#include <math.h>
#include <stdint.h>

typedef __bf16 bf16_t;
typedef __bf16 bf16x2 __attribute__((ext_vector_type(2)));
typedef __bf16 bf16x4 __attribute__((ext_vector_type(4)));
typedef __bf16 bf16x8 __attribute__((ext_vector_type(8)));
typedef float f32x4 __attribute__((ext_vector_type(4)));

#define NB   32
#define SEQ  2048
#define HD   128
#define SCALE 0.08838834764831845f

// ============================ prep kernel =================================
// blocks 0..2047:    Qs = bf16(Q * SCALE)
// blocks 2048..4095: Kb = bf16(K)
// blocks 4096..6143: Vt = bf16(V) transposed [B][D][S]
__global__ __launch_bounds__(256) void prep_kernel(
    const float* __restrict__ Q, const float* __restrict__ K,
    const float* __restrict__ V, bf16_t* __restrict__ Qs,
    bf16_t* __restrict__ Kb, bf16_t* __restrict__ Vt)
{
  const int b = blockIdx.x;
  const int tid = threadIdx.x;
  if (b < 4096) {
    const bool isQ = (b < 2048);
    const float* src = isQ ? Q : K;
    bf16_t* dst = isQ ? Qs : Kb;
    const float sc = isQ ? SCALE : 1.0f;
    size_t base4 = (size_t)(isQ ? b : b - 2048) * 1024;
#pragma unroll
    for (int i = 0; i < 4; ++i) {
      size_t idx = base4 + tid + i * 256;
      float4 x = ((const float4*)src)[idx];
      bf16x4 y;
      y[0] = (bf16_t)(x.x * sc); y[1] = (bf16_t)(x.y * sc);
      y[2] = (bf16_t)(x.z * sc); y[3] = (bf16_t)(x.w * sc);
      ((bf16x4*)dst)[idx] = y;
    }
  } else {
    __shared__ __attribute__((aligned(16))) bf16_t tile[64][72];  // [d][s]
    const int bt = b - 4096;
    const int batch = bt >> 6;
    const int rem = bt & 63;
    const int s0 = (rem >> 1) * 64;
    const int d0 = (rem & 1) * 64;
#pragma unroll
    for (int i = 0; i < 4; ++i) {
      int e = tid + i * 256;
      int s = e >> 4, dq = e & 15;
      float4 x = *(const float4*)&V[((size_t)batch * SEQ + s0 + s) * HD + d0 + dq * 4];
      tile[dq * 4 + 0][s] = (bf16_t)x.x;
      tile[dq * 4 + 1][s] = (bf16_t)x.y;
      tile[dq * 4 + 2][s] = (bf16_t)x.z;
      tile[dq * 4 + 3][s] = (bf16_t)x.w;
    }
    __syncthreads();
#pragma unroll
    for (int i = 0; i < 2; ++i) {
      int g = tid + i * 256;
      int d = g >> 3, sg = g & 7;
      bf16x8 w = *(const bf16x8*)&tile[d][sg * 8];
      *(bf16x8*)&Vt[((size_t)batch * HD + d0 + d) * SEQ + s0 + sg * 8] = w;
    }
  }
}

// ============================ main kernel =================================
// R2's PROVEN compute core (16x16x32, Psh round-trip, online-max softmax),
// staging swapped to prep'd bf16 + XOR-swizzled global_load_lds double-buffer.
// Grid 1024 (batch*32 q-tiles of 64), 256 threads.
__global__ __launch_bounds__(256) void fa5_kernel(
    const bf16_t* __restrict__ Qs, const bf16_t* __restrict__ Kbf,
    const bf16_t* __restrict__ Vt, float* __restrict__ O)
{
  // K tile: [key(64)][d(128)] in 16B granules, physical granule = logical ^ (key&15)
  // V tile: [d(128)][key(64)] in 16B granules, physical granule = logical ^ (d&7)
  __shared__ __attribute__((aligned(16))) bf16_t Ksw[2][64 * 128];   // 16KB x2
  __shared__ __attribute__((aligned(16))) bf16_t Vsw[2][128 * 64];   // 16KB x2
  __shared__ __attribute__((aligned(16))) bf16_t Psh[4][16][72];     // 9KB

  const int tid  = threadIdx.x;
  const int lane = tid & 63;
  const int wq   = tid >> 6;
  const int quad = lane >> 4;
  const int l15  = lane & 15;

  const int batch = blockIdx.x >> 5;
  const int qt    = blockIdx.x & 31;

  const bf16_t* Qb = Qs + ((size_t)batch * SEQ + qt * 64) * HD;
  const bf16_t* Kb = Kbf + (size_t)batch * SEQ * HD;
  const bf16_t* Vb = Vt + (size_t)batch * HD * SEQ;
  float*        Ob = O + ((size_t)batch * SEQ + qt * 64) * HD;

  // ---- Q fragments (B-operand for S^T): B[n=q=l15][k=d=kf*32+quad*8+j] ----
  bf16x8 aq[4];
  {
    const int qrow = wq * 16 + l15;
#pragma unroll
    for (int kf = 0; kf < 4; ++kf)
      aq[kf] = *(const bf16x8*)&Qb[(size_t)qrow * HD + kf * 32 + quad * 8];
  }

  f32x4 o[8];
#pragma unroll
  for (int t = 0; t < 8; ++t) { o[t][0]=0.f; o[t][1]=0.f; o[t][2]=0.f; o[t][3]=0.f; }
  float m_r = -INFINITY, l_r = 0.0f;

  // ---- DMA staging: each wave stages 16 K-rows and 32 V-rows ----
  auto stage = [&](int buf, int kb) {
#pragma unroll
    for (int i = 0; i < 4; ++i) {
      int row = wq * 16 + i * 4 + (lane >> 4);
      int gk = (lane & 15) ^ (row & 15);
      const bf16_t* gp = Kb + (size_t)(kb + row) * HD + gk * 8;
      __builtin_amdgcn_global_load_lds(
          (const __attribute__((address_space(1))) void*)gp,
          (__attribute__((address_space(3))) void*)&Ksw[buf][(wq * 16 + i * 4) * 128],
          16, 0, 0);
    }
#pragma unroll
    for (int i = 0; i < 4; ++i) {
      int d = wq * 32 + i * 8 + (lane >> 3);
      int gv = (lane & 7) ^ (d & 7);
      const bf16_t* gp = Vb + (size_t)d * SEQ + kb + gv * 8;
      __builtin_amdgcn_global_load_lds(
          (const __attribute__((address_space(1))) void*)gp,
          (__attribute__((address_space(3))) void*)&Vsw[buf][(wq * 32 + i * 8) * 64],
          16, 0, 0);
    }
  };

  stage(0, 0);

  for (int it = 0; it < SEQ / 64; ++it) {
    __syncthreads();  // drains own DMA (vmcnt0 before barrier) + prior LDS reads
    if (it + 1 < SEQ / 64) stage((it + 1) & 1, (it + 1) * 64);

    const bf16_t* Ks = &Ksw[it & 1][0];
    const bf16_t* Vs = &Vsw[it & 1][0];

    // ---- S^T = K Q^T (R2-proven layout): A=K, B=Q ----
    f32x4 s[4];
#pragma unroll
    for (int ct = 0; ct < 4; ++ct) { s[ct][0]=0.f; s[ct][1]=0.f; s[ct][2]=0.f; s[ct][3]=0.f; }
#pragma unroll
    for (int kf = 0; kf < 4; ++kf)
#pragma unroll
      for (int ct = 0; ct < 4; ++ct) {
        int row = ct * 16 + l15;
        bf16x8 ak = *(const bf16x8*)&Ks[row * 128 + (((kf * 4 + quad) ^ l15) * 8)];
        s[ct] = __builtin_amdgcn_mfma_f32_16x16x32_bf16(ak, aq[kf], s[ct], 0, 0, 0);
      }

    // ---- online softmax (R2-identical) ----
    float mx = s[0][0];
#pragma unroll
    for (int ct = 0; ct < 4; ++ct)
#pragma unroll
      for (int r = 0; r < 4; ++r) mx = fmaxf(mx, s[ct][r]);
    mx = fmaxf(mx, __shfl_xor(mx, 16));
    mx = fmaxf(mx, __shfl_xor(mx, 32));
    float mnew = fmaxf(m_r, mx);
    float alpha = __expf(m_r - mnew);
    m_r = mnew;
    float ls = 0.f;
#pragma unroll
    for (int ct = 0; ct < 4; ++ct)
#pragma unroll
      for (int r = 0; r < 4; ++r) {
        float p = __expf(s[ct][r] - mnew);
        s[ct][r] = p; ls += p;
      }
    ls += __shfl_xor(ls, 16);
    ls += __shfl_xor(ls, 32);
    l_r = l_r * alpha + ls;

    // ---- P round-trip through Psh (R2-identical) ----
#pragma unroll
    for (int ct = 0; ct < 4; ++ct) {
      bf16x4 pp;
      pp[0]=(bf16_t)s[ct][0]; pp[1]=(bf16_t)s[ct][1];
      pp[2]=(bf16_t)s[ct][2]; pp[3]=(bf16_t)s[ct][3];
      *(bf16x4*)&Psh[wq][l15][ct * 16 + quad * 4] = pp;
    }
    asm volatile("s_waitcnt lgkmcnt(0)" ::: "memory");
    bf16x8 ap0 = *(const bf16x8*)&Psh[wq][l15][quad * 8];
    bf16x8 ap1 = *(const bf16x8*)&Psh[wq][l15][32 + quad * 8];

    // ---- rescale O, O^T += V^T P^T ----
#pragma unroll
    for (int t = 0; t < 8; ++t) {
      o[t][0]*=alpha; o[t][1]*=alpha; o[t][2]*=alpha; o[t][3]*=alpha;
    }
#pragma unroll
    for (int t = 0; t < 8; ++t) {
      int d = t * 16 + l15;
      bf16x8 av0 = *(const bf16x8*)&Vs[d * 64 + ((quad ^ (l15 & 7)) * 8)];
      o[t] = __builtin_amdgcn_mfma_f32_16x16x32_bf16(av0, ap0, o[t], 0, 0, 0);
      bf16x8 av1 = *(const bf16x8*)&Vs[d * 64 + (((4 + quad) ^ (l15 & 7)) * 8)];
      o[t] = __builtin_amdgcn_mfma_f32_16x16x32_bf16(av1, ap1, o[t], 0, 0, 0);
    }
  }

  // ---- epilogue (R2-identical) ----
  float inv = 1.0f / l_r;
  const int qrow = wq * 16 + l15;
#pragma unroll
  for (int t = 0; t < 8; ++t) {
    float4 w;
    w.x = o[t][0]*inv; w.y = o[t][1]*inv; w.z = o[t][2]*inv; w.w = o[t][3]*inv;
    *(float4*)&Ob[(size_t)qrow * HD + t * 16 + quad * 4] = w;
  }
}

// ===================== fallback (proven R2 kernel) ========================
#define BM   64
#define BN   64
#define KPAD 8
#define VPAD 8
#define PPAD 8

__global__ __launch_bounds__(256) void fa_fallback(
    const float* __restrict__ Q, const float* __restrict__ K,
    const float* __restrict__ V, float* __restrict__ O)
{
  __shared__ __attribute__((aligned(16))) bf16_t Ksh[BN][HD + KPAD];
  __shared__ __attribute__((aligned(16))) bf16_t Vsh[HD][BN + VPAD];
  __shared__ __attribute__((aligned(16))) bf16_t Psh[4][16][BN + PPAD];

  const int tid = threadIdx.x;
  const int lane = tid & 63;
  const int wq = tid >> 6;
  const int quad = lane >> 4;
  const int l15 = lane & 15;
  const int bid = blockIdx.x;
  const int batch = bid >> 5;
  const int qt = bid & 31;

  const float* Qb = Q + (size_t)batch * SEQ * HD + (size_t)qt * BM * HD;
  const float* Kb = K + (size_t)batch * SEQ * HD;
  const float* Vb = V + (size_t)batch * SEQ * HD;
  float* Ob = O + (size_t)batch * SEQ * HD + (size_t)qt * BM * HD;

  bf16x8 aq[4];
  {
    const int qrow = wq * 16 + l15;
#pragma unroll
    for (int kf = 0; kf < 4; ++kf) {
      const float* qp = Qb + (size_t)qrow * HD + kf * 32 + quad * 8;
      float4 x0 = *(const float4*)(qp);
      float4 x1 = *(const float4*)(qp + 4);
      bf16x8 a;
      a[0] = (bf16_t)(x0.x * SCALE); a[1] = (bf16_t)(x0.y * SCALE);
      a[2] = (bf16_t)(x0.z * SCALE); a[3] = (bf16_t)(x0.w * SCALE);
      a[4] = (bf16_t)(x1.x * SCALE); a[5] = (bf16_t)(x1.y * SCALE);
      a[6] = (bf16_t)(x1.z * SCALE); a[7] = (bf16_t)(x1.w * SCALE);
      aq[kf] = a;
    }
  }

  f32x4 o[8];
#pragma unroll
  for (int t = 0; t < 8; ++t) { o[t][0]=0.f; o[t][1]=0.f; o[t][2]=0.f; o[t][3]=0.f; }
  float m_r = -INFINITY, l_r = 0.0f;
  const int vkp = (tid & 31) * 2;
  const int vg = tid >> 5;
  float4 kreg[8], vreg[8];

#pragma unroll
  for (int i = 0; i < 8; ++i) {
    int v = tid + i * 256, row = v >> 5, c4 = (v & 31) * 4;
    kreg[i] = *(const float4*)(Kb + (size_t)row * HD + c4);
  }
#pragma unroll
  for (int i = 0; i < 4; ++i) {
    int d0 = (vg + i * 8) * 4;
    const float* vp0 = Vb + (size_t)vkp * HD + d0;
    vreg[2 * i] = *(const float4*)vp0;
    vreg[2 * i + 1] = *(const float4*)(vp0 + HD);
  }

  for (int kb = 0; kb < SEQ; kb += BN) {
    __syncthreads();
#pragma unroll
    for (int i = 0; i < 8; ++i) {
      int v = tid + i * 256, row = v >> 5, c4 = (v & 31) * 4;
      float4 kv = kreg[i];
      bf16x4 kk;
      kk[0]=(bf16_t)kv.x; kk[1]=(bf16_t)kv.y; kk[2]=(bf16_t)kv.z; kk[3]=(bf16_t)kv.w;
      *(bf16x4*)&Ksh[row][c4] = kk;
    }
#pragma unroll
    for (int i = 0; i < 4; ++i) {
      int d0 = (vg + i * 8) * 4;
      float4 a0 = vreg[2 * i], a1 = vreg[2 * i + 1];
      bf16x2 p0; p0[0]=(bf16_t)a0.x; p0[1]=(bf16_t)a1.x;
      bf16x2 p1; p1[0]=(bf16_t)a0.y; p1[1]=(bf16_t)a1.y;
      bf16x2 p2; p2[0]=(bf16_t)a0.z; p2[1]=(bf16_t)a1.z;
      bf16x2 p3; p3[0]=(bf16_t)a0.w; p3[1]=(bf16_t)a1.w;
      *(bf16x2*)&Vsh[d0 + 0][vkp] = p0;
      *(bf16x2*)&Vsh[d0 + 1][vkp] = p1;
      *(bf16x2*)&Vsh[d0 + 2][vkp] = p2;
      *(bf16x2*)&Vsh[d0 + 3][vkp] = p3;
    }
    __syncthreads();

    const int kbn = kb + BN;
    if (kbn < SEQ) {
#pragma unroll
      for (int i = 0; i < 8; ++i) {
        int v = tid + i * 256, row = v >> 5, c4 = (v & 31) * 4;
        kreg[i] = *(const float4*)(Kb + (size_t)(kbn + row) * HD + c4);
      }
#pragma unroll
      for (int i = 0; i < 4; ++i) {
        int d0 = (vg + i * 8) * 4;
        const float* vp0 = Vb + (size_t)(kbn + vkp) * HD + d0;
        vreg[2 * i] = *(const float4*)vp0;
        vreg[2 * i + 1] = *(const float4*)(vp0 + HD);
      }
    }

    f32x4 s[4];
#pragma unroll
    for (int ct = 0; ct < 4; ++ct) { s[ct][0]=0.f; s[ct][1]=0.f; s[ct][2]=0.f; s[ct][3]=0.f; }
#pragma unroll
    for (int kf = 0; kf < 4; ++kf)
#pragma unroll
      for (int ct = 0; ct < 4; ++ct) {
        bf16x8 ak = *(const bf16x8*)&Ksh[ct * 16 + l15][kf * 32 + quad * 8];
        s[ct] = __builtin_amdgcn_mfma_f32_16x16x32_bf16(ak, aq[kf], s[ct], 0, 0, 0);
      }

    float mx = s[0][0];
#pragma unroll
    for (int ct = 0; ct < 4; ++ct)
#pragma unroll
      for (int r = 0; r < 4; ++r) mx = fmaxf(mx, s[ct][r]);
    mx = fmaxf(mx, __shfl_xor(mx, 16));
    mx = fmaxf(mx, __shfl_xor(mx, 32));
    float mnew = fmaxf(m_r, mx);
    float alpha = __expf(m_r - mnew);
    m_r = mnew;
    float ls = 0.f;
#pragma unroll
    for (int ct = 0; ct < 4; ++ct)
#pragma unroll
      for (int r = 0; r < 4; ++r) {
        float p = __expf(s[ct][r] - mnew);
        s[ct][r] = p; ls += p;
      }
    ls += __shfl_xor(ls, 16);
    ls += __shfl_xor(ls, 32);
    l_r = l_r * alpha + ls;

#pragma unroll
    for (int ct = 0; ct < 4; ++ct) {
      bf16x4 pp;
      pp[0]=(bf16_t)s[ct][0]; pp[1]=(bf16_t)s[ct][1];
      pp[2]=(bf16_t)s[ct][2]; pp[3]=(bf16_t)s[ct][3];
      *(bf16x4*)&Psh[wq][l15][ct * 16 + quad * 4] = pp;
    }
    asm volatile("s_waitcnt lgkmcnt(0)" ::: "memory");
    bf16x8 ap0 = *(const bf16x8*)&Psh[wq][l15][quad * 8];
    bf16x8 ap1 = *(const bf16x8*)&Psh[wq][l15][32 + quad * 8];

#pragma unroll
    for (int t = 0; t < 8; ++t) {
      o[t][0]*=alpha; o[t][1]*=alpha; o[t][2]*=alpha; o[t][3]*=alpha;
    }
#pragma unroll
    for (int t = 0; t < 8; ++t) {
      bf16x8 av0 = *(const bf16x8*)&Vsh[t * 16 + l15][quad * 8];
      o[t] = __builtin_amdgcn_mfma_f32_16x16x32_bf16(av0, ap0, o[t], 0, 0, 0);
      bf16x8 av1 = *(const bf16x8*)&Vsh[t * 16 + l15][32 + quad * 8];
      o[t] = __builtin_amdgcn_mfma_f32_16x16x32_bf16(av1, ap1, o[t], 0, 0, 0);
    }
  }

  float inv = 1.0f / l_r;
  const int qrow = wq * 16 + l15;
#pragma unroll
  for (int t = 0; t < 8; ++t) {
    float4 w;
    w.x = o[t][0]*inv; w.y = o[t][1]*inv; w.z = o[t][2]*inv; w.w = o[t][3]*inv;
    *(float4*)&Ob[(size_t)qrow * HD + t * 16 + quad * 4] = w;
  }
}

extern "C" void kernel_launch(void* const* d_in, const int* in_sizes, int n_in,
                              void* d_out, int out_size, void* d_ws, size_t ws_size,
                              hipStream_t stream) {
  const float* q = (const float*)d_in[0];
  const float* k = (const float*)d_in[1];
  const float* v = (const float*)d_in[2];
  float* out = (float*)d_out;

  const size_t elems = (size_t)NB * SEQ * HD;          // 8388608
  const size_t need = elems * 2 * 3;                   // 48 MiB bf16 x3

  if (ws_size >= need) {
    bf16_t* Qs = (bf16_t*)d_ws;
    bf16_t* Kb = Qs + elems;
    bf16_t* Vt = Kb + elems;
    prep_kernel<<<6144, 256, 0, stream>>>(q, k, v, Qs, Kb, Vt);
    fa5_kernel<<<NB * (SEQ / 64), 256, 0, stream>>>(Qs, Kb, Vt, out);
  } else {
    fa_fallback<<<NB * (SEQ / BM), 256, 0, stream>>>(q, k, v, out);
  }
}